// Round 10
// baseline (170.539 us; speedup 1.0000x reference)
//
#include <hip/hip_runtime.h>
#include <hip/hip_bf16.h>

// EfficientAttention: B=4, N=8192, C=384, H=6, D=64
// Round 10: out_gemm restructured to single-barrier (B c-slice staged once in
// LDS, A-frags direct from global q — L3-resident); wprep absorbs the kvraw
// memset. proj/kw unchanged from round 9.

#define B 4
#define N 8192
#define C 384
#define H 6
#define D 64
#define BH (B * H)   // 24
#define BN (B * N)   // 32768

typedef __attribute__((ext_vector_type(8))) short short8;
typedef __attribute__((ext_vector_type(4))) float f32x4;

__device__ inline unsigned short f2bf(float f) {
    unsigned int u = __float_as_uint(f);
    unsigned int r = (u + 0x7fff + ((u >> 16) & 1)) >> 16;   // RNE
    return (unsigned short)r;
}

// ---------------------------------------------------------------------------
// Kernel 0: transpose the three weight sets to bf16 B-operand layout, and
// zero kvraw/Sg (absorbs the old memset dispatch).
// Wt layout: [mat][h][e][d] bf16, value = W[d][e].
// ---------------------------------------------------------------------------
__global__ void wprep(const float* __restrict__ Wq, const float* __restrict__ Wk,
                      const float* __restrict__ Wv, unsigned short* __restrict__ Wt,
                      float* __restrict__ kvzero)
{
    __shared__ float tmp[64][65];
    const int m = blockIdx.x / H;
    const int h = blockIdx.x % H;
    const float* in = (m == 0 ? Wq : m == 1 ? Wk : Wv) + h * 64 * 64;
    const int t = threadIdx.x;
    for (int d = 0; d < 64; ++d) tmp[d][t] = in[d * 64 + t];   // tmp[d][e]
    __syncthreads();
    const size_t base = ((size_t)(m * H + h)) * 64 * 64;
    for (int e = 0; e < 64; ++e)
        Wt[base + e * 64 + t] = f2bf(tmp[t][e]);   // out[e][d=t] = W[d=t][e]
    // zero kvraw [BH*4096] + Sg [BH*64] = 99840 floats across 18 blocks
    const int ztot = BH * 4096 + BH * 64;
    for (int i = blockIdx.x * 64 + t; i < ztot; i += 18 * 64)
        kvzero[i] = 0.f;
}

// ---------------------------------------------------------------------------
// Kernel 1 (MFMA): per-head QKV projection (bf16) + q softmax + fused
// kv-partial accumulation + S column sums.
// grid = BH * (N/256) = 768 blocks, 256 threads. LDS 34816 B.
// ---------------------------------------------------------------------------
__global__ __launch_bounds__(256, 2) void proj_kernel(
    const float* __restrict__ x, const unsigned short* __restrict__ Wt,
    const float* __restrict__ bq, const float* __restrict__ bk,
    const float* __restrict__ bv,
    unsigned short* __restrict__ qout,
    float* __restrict__ kvraw, float* __restrict__ Sg)
{
    __shared__ __align__(16) char smem[34816];
    unsigned short* W_s = (unsigned short*)smem;       // 3 x [64][64], swizzled
    unsigned short* qbuf = (unsigned short*)(smem + 24576); // per-wave [16][72]
    float* kvred = (float*)smem;                       // overlay: [4][32][66]
    float* sred  = (float*)(smem + 33792);             // overlay: [4][64]

    const int blk = blockIdx.x;
    const int nb  = blk & 31;            // N/256 = 32 chunks
    const int bh  = blk >> 5;
    const int b   = bh / H;
    const int h   = bh % H;
    const int n0  = nb * 256;
    const int t   = threadIdx.x;
    const int lane = t & 63;
    const int w   = t >> 6;
    const int lq  = lane & 15;
    const int qd  = lane >> 4;

    // ---- stage 3 weight parts, XOR-swizzled chunks within each row ----
    {
        const size_t hb = (size_t)h * 4096;
        for (int id = t; id < 512; id += 256) {
            int e = id >> 3, c = id & 7;
            int dc = ((c ^ (e & 7)) * 8);
            #pragma unroll
            for (int m = 0; m < 3; ++m)
                *(uint4*)&W_s[m * 4096 + e * 64 + dc] =
                    *(const uint4*)(Wt + (size_t)m * H * 4096 + hb + e * 64 + c * 8);
        }
    }

    float bqv[4], bkv[4], bvv[4];
    #pragma unroll
    for (int j = 0; j < 4; ++j) {
        int col = j * 16 + lq;
        bqv[j] = bq[h * D + col];
        bkv[j] = bk[h * D + col];
        bvv[j] = bv[h * D + col];
    }

    unsigned short* qw = qbuf + w * 1152;   // this wave's [16][72] region

    __syncthreads();   // W_s ready

    f32x4 kvacc[4][4] = {};
    float sacc[4] = {};

    for (int sub = 0; sub < 4; ++sub) {
        const int ns = n0 + sub * 64;

        // ---- A-fragment direct from global: row w*16+lq, k-chunks qd*8 ----
        const float* ap = x + (size_t)(b * N + ns + w * 16 + lq) * C + h * D + qd * 8;
        short8 af[2];
        {
            float av[16];
            *(float4*)&av[0]  = *(const float4*)ap;
            *(float4*)&av[4]  = *(const float4*)(ap + 4);
            *(float4*)&av[8]  = *(const float4*)(ap + 32);
            *(float4*)&av[12] = *(const float4*)(ap + 36);
            #pragma unroll
            for (int ck = 0; ck < 2; ++ck)
                #pragma unroll
                for (int i = 0; i < 8; ++i)
                    af[ck][i] = (short)f2bf(av[ck * 8 + i]);
        }

        // ---- m = 0 (q): MFMA -> softmax -> qbuf (wave-local) -> global ----
        {
            f32x4 acc[4] = {};
            #pragma unroll
            for (int ck = 0; ck < 2; ++ck)
                #pragma unroll
                for (int j = 0; j < 4; ++j) {
                    const int pc = ((ck * 4 + qd) ^ (lq & 7)) * 8;
                    short8 bw = *(const short8*)&W_s[(j * 16 + lq) * 64 + pc];
                    acc[j] = __builtin_amdgcn_mfma_f32_16x16x32_bf16(af[ck], bw, acc[j], 0, 0, 0);
                }
            #pragma unroll
            for (int r = 0; r < 4; ++r) {
                float qv[4];
                #pragma unroll
                for (int j = 0; j < 4; ++j) qv[j] = acc[j][r] + bqv[j];
                float mx = fmaxf(fmaxf(qv[0], qv[1]), fmaxf(qv[2], qv[3]));
                #pragma unroll
                for (int msk = 1; msk < 16; msk <<= 1) mx = fmaxf(mx, __shfl_xor(mx, msk));
                float e0 = __expf(qv[0] - mx), e1 = __expf(qv[1] - mx);
                float e2 = __expf(qv[2] - mx), e3 = __expf(qv[3] - mx);
                float s = e0 + e1 + e2 + e3;
                #pragma unroll
                for (int msk = 1; msk < 16; msk <<= 1) s += __shfl_xor(s, msk);
                float inv = 1.f / s;
                const int row = qd * 4 + r;
                qw[row * 72 + 0 * 16 + lq] = f2bf(e0 * inv);
                qw[row * 72 + 1 * 16 + lq] = f2bf(e1 * inv);
                qw[row * 72 + 2 * 16 + lq] = f2bf(e2 * inv);
                qw[row * 72 + 3 * 16 + lq] = f2bf(e3 * inv);
            }
            // wave-local readback -> coalesced 16B global stores (no barrier)
            const size_t gbase = (size_t)bh * N + ns + w * 16;
            #pragma unroll
            for (int rep = 0; rep < 2; ++rep) {
                int flat = rep * 64 + lane;
                int row = flat >> 3, c8 = flat & 7;
                *(uint4*)&qout[(gbase + row) * 64 + c8 * 8] =
                    *(uint4*)&qw[row * 72 + c8 * 8];
            }
        }
        __builtin_amdgcn_sched_barrier(0);

        // ---- m = 1 (k): MFMA -> exp -> kfrag + S partial ----
        short8 kfrag[4];
        {
            f32x4 acc[4] = {};
            #pragma unroll
            for (int ck = 0; ck < 2; ++ck)
                #pragma unroll
                for (int j = 0; j < 4; ++j) {
                    const int pc = ((ck * 4 + qd) ^ (lq & 7)) * 8;
                    short8 bw = *(const short8*)&W_s[4096 + (j * 16 + lq) * 64 + pc];
                    acc[j] = __builtin_amdgcn_mfma_f32_16x16x32_bf16(af[ck], bw, acc[j], 0, 0, 0);
                }
            #pragma unroll
            for (int j = 0; j < 4; ++j) {
                float e0 = __expf(acc[j][0] + bkv[j]);
                float e1 = __expf(acc[j][1] + bkv[j]);
                float e2 = __expf(acc[j][2] + bkv[j]);
                float e3 = __expf(acc[j][3] + bkv[j]);
                float cs = e0 + e1 + e2 + e3;
                cs += __shfl_xor(cs, 16);
                cs += __shfl_xor(cs, 32);
                sacc[j] += cs;
                kfrag[j] = short8{(short)f2bf(e0), (short)f2bf(e1),
                                  (short)f2bf(e2), (short)f2bf(e3), 0, 0, 0, 0};
            }
        }
        __builtin_amdgcn_sched_barrier(0);

        // ---- m = 2 (v): MFMA -> vfrag -> kv accumulate ----
        {
            f32x4 acc[4] = {};
            #pragma unroll
            for (int ck = 0; ck < 2; ++ck)
                #pragma unroll
                for (int j = 0; j < 4; ++j) {
                    const int pc = ((ck * 4 + qd) ^ (lq & 7)) * 8;
                    short8 bw = *(const short8*)&W_s[2 * 4096 + (j * 16 + lq) * 64 + pc];
                    acc[j] = __builtin_amdgcn_mfma_f32_16x16x32_bf16(af[ck], bw, acc[j], 0, 0, 0);
                }
            short8 vfrag[4];
            #pragma unroll
            for (int j = 0; j < 4; ++j) {
                float v0 = (acc[j][0] + bvv[j]) * 0.125f;
                float v1 = (acc[j][1] + bvv[j]) * 0.125f;
                float v2 = (acc[j][2] + bvv[j]) * 0.125f;
                float v3 = (acc[j][3] + bvv[j]) * 0.125f;
                vfrag[j] = short8{(short)f2bf(v0), (short)f2bf(v1),
                                  (short)f2bf(v2), (short)f2bf(v3), 0, 0, 0, 0};
            }
            #pragma unroll
            for (int i = 0; i < 4; ++i)
                #pragma unroll
                for (int j = 0; j < 4; ++j)
                    kvacc[i][j] = __builtin_amdgcn_mfma_f32_16x16x32_bf16(
                        kfrag[i], vfrag[j], kvacc[i][j], 0, 0, 0);
        }
        __builtin_amdgcn_sched_barrier(0);
    }

    __syncthreads();   // all W_s/qbuf use done -> overlay region free

    // ---- cross-wave reduce in 2 halves (32 d-rows each), then atomics ----
    #pragma unroll
    for (int half = 0; half < 2; ++half) {
        #pragma unroll
        for (int i2 = 0; i2 < 2; ++i2) {
            const int ii = half * 2 + i2;
            #pragma unroll
            for (int j = 0; j < 4; ++j)
                #pragma unroll
                for (int r = 0; r < 4; ++r)
                    kvred[w * 2112 + (i2 * 16 + qd * 4 + r) * 66 + j * 16 + lq] =
                        kvacc[ii][j][r];
        }
        if (half == 0 && qd == 0) {
            #pragma unroll
            for (int j = 0; j < 4; ++j) sred[w * 64 + j * 16 + lq] = sacc[j];
        }
        __syncthreads();
        for (int idx = t; idx < 2048; idx += 256) {
            int dl = idx >> 6, e = idx & 63;
            float s = kvred[dl * 66 + e] + kvred[2112 + dl * 66 + e]
                    + kvred[2 * 2112 + dl * 66 + e] + kvred[3 * 2112 + dl * 66 + e];
            atomicAdd(&kvraw[bh * 4096 + (half * 32 + dl) * 64 + e], s);
        }
        if (half == 1 && t < 64) {
            float s = sred[t] + sred[64 + t] + sred[128 + t] + sred[192 + t];
            atomicAdd(&Sg[bh * 64 + t], s);
        }
        if (half == 0) __syncthreads();
    }
}

// ---------------------------------------------------------------------------
// Kernel 2: KWT[b][c][h*64+d] = sum_e (kvraw[bh][d][e]/S[d]) * Wp[c][h*64+e]
// ---------------------------------------------------------------------------
__global__ __launch_bounds__(256) void kw_kernel(
    const float* __restrict__ kvraw, const float* __restrict__ Sg,
    const float* __restrict__ Wp, unsigned short* __restrict__ KWT)
{
    __shared__ float kv_s[64 * 68];   // [e][d]
    __shared__ float w_s[64 * 68];    // [e][c]
    __shared__ float rS_s[64];
    const int bh = blockIdx.x / (C / 64);
    const int ct = blockIdx.x % (C / 64);
    const int b = bh / H, h = bh % H;
    const int c0 = ct * 64;
    const int t = threadIdx.x, dg = t >> 4, cg = t & 15;

    if (t < 64) rS_s[t] = 1.f / Sg[bh * 64 + t];
    __syncthreads();

    for (int i = t; i < 4096; i += 256) {
        int row = i >> 6, e = i & 63;
        kv_s[e * 68 + row] = kvraw[bh * (D * D) + row * 64 + e] * rS_s[row];
        w_s[e * 68 + row]  = Wp[(size_t)(c0 + row) * C + h * 64 + e];
    }
    __syncthreads();

    float acc[4][4] = {};
    for (int e = 0; e < 64; ++e) {
        float4 a = *(float4*)&kv_s[e * 68 + dg * 4];
        float4 w = *(float4*)&w_s[e * 68 + cg * 4];
        const float a4[4] = {a.x, a.y, a.z, a.w};
        const float w4[4] = {w.x, w.y, w.z, w.w};
        #pragma unroll
        for (int i = 0; i < 4; ++i)
            #pragma unroll
            for (int j = 0; j < 4; ++j) acc[i][j] += a4[i] * w4[j];
    }
    #pragma unroll
    for (int i = 0; i < 4; ++i)
        #pragma unroll
        for (int j = 0; j < 4; ++j) {
            int d = dg * 4 + i, c = c0 + cg * 4 + j;
            KWT[((size_t)b * C + c) * (H * D) + h * 64 + d] = f2bf(acc[i][j]);
        }
}

// ---------------------------------------------------------------------------
// Kernel 3 (MFMA): out[m][c] = sum_k q[m][k] * KWT[c][k] + bp[c]
// Single-barrier: B c-slice [64][384] staged once (49 KB); A-frags direct
// from global q (L3-resident). grid = (BN/128)*(C/64) = 1536, 256 thr.
// Wave = 32 rows x 64 cols, acc[2][4], 96 MFMAs, 0 in-loop barriers.
// ---------------------------------------------------------------------------
__global__ __launch_bounds__(256, 3) void out_gemm(
    const unsigned short* __restrict__ q, const unsigned short* __restrict__ KWT,
    const float* __restrict__ bp, float* __restrict__ out)
{
    __shared__ __align__(16) unsigned short B_s[64 * 392];   // [c][k], pad 392

    const int mt = blockIdx.x / (C / 64);
    const int ct = blockIdx.x % (C / 64);
    const int m0 = mt * 128, c0 = ct * 64;
    const int b  = m0 >> 13;            // N = 8192
    const int t  = threadIdx.x;
    const int lane = t & 63;
    const int w  = t >> 6;
    const int lq = lane & 15;
    const int qd = lane >> 4;

    // stage B: 64 c-rows x 384 k (48 uint4-chunks per row)
    for (int id = t; id < 64 * 48; id += 256) {
        int r = id / 48, c8 = id % 48;
        *(uint4*)&B_s[r * 392 + c8 * 8] =
            *(const uint4*)(KWT + ((size_t)b * C + c0 + r) * (H * D) + c8 * 8);
    }
    __syncthreads();

    f32x4 acc[2][4] = {};
    const int nw = (m0 & (N - 1)) + w * 32;   // wave's first row within batch

    for (int h = 0; h < H; ++h) {
        const unsigned short* qb = q + ((size_t)(b * H + h) * N + nw) * D;
        // B-frags for this head: 4 c-frags x 2 k-chunks
        short8 bfr[4][2];
        #pragma unroll
        for (int j = 0; j < 4; ++j) {
            const unsigned short* br = B_s + (j * 16 + lq) * 392 + h * 64 + qd * 8;
            bfr[j][0] = *(const short8*)br;
            bfr[j][1] = *(const short8*)(br + 32);
        }
        #pragma unroll
        for (int i = 0; i < 2; ++i) {
            const unsigned short* ar = qb + (size_t)(i * 16 + lq) * D + qd * 8;
            short8 a0 = *(const short8*)ar;
            short8 a1 = *(const short8*)(ar + 32);
            #pragma unroll
            for (int j = 0; j < 4; ++j) {
                acc[i][j] = __builtin_amdgcn_mfma_f32_16x16x32_bf16(a0, bfr[j][0], acc[i][j], 0, 0, 0);
                acc[i][j] = __builtin_amdgcn_mfma_f32_16x16x32_bf16(a1, bfr[j][1], acc[i][j], 0, 0, 0);
            }
        }
    }

    float bpv[4];
    #pragma unroll
    for (int j = 0; j < 4; ++j) bpv[j] = bp[c0 + j * 16 + lq];

    #pragma unroll
    for (int i = 0; i < 2; ++i) {
        #pragma unroll
        for (int r = 0; r < 4; ++r) {
            size_t row = (size_t)m0 + w * 32 + i * 16 + qd * 4 + r;
            float* orow = out + row * C + c0;
            #pragma unroll
            for (int j = 0; j < 4; ++j)
                orow[j * 16 + lq] = acc[i][j][r] + bpv[j];
        }
    }
}

// ---------------------------------------------------------------------------
extern "C" void kernel_launch(void* const* d_in, const int* in_sizes, int n_in,
                              void* d_out, int out_size, void* d_ws, size_t ws_size,
                              hipStream_t stream)
{
    const float* x  = (const float*)d_in[0];
    const float* Wq = (const float*)d_in[1];
    const float* bq = (const float*)d_in[2];
    const float* Wk = (const float*)d_in[3];
    const float* bk = (const float*)d_in[4];
    const float* Wv = (const float*)d_in[5];
    const float* bv = (const float*)d_in[6];
    const float* Wp = (const float*)d_in[7];
    const float* bp = (const float*)d_in[8];
    float* out = (float*)d_out;

    const size_t SZ = (size_t)B * H * N * D;
    float* ws   = (float*)d_ws;
    unsigned short* q = (unsigned short*)ws;          // [BH, N, D] bf16
    float* kvraw = ws + SZ;                           // [BH, 64, 64] fp32
    float* Sg    = kvraw + (size_t)BH * D * D;        // [BH, 64] fp32 (contiguous after kvraw)
    unsigned short* KWT = (unsigned short*)(Sg + BH * 64);   // [B, C, H*D] bf16
    unsigned short* Wt  = KWT + (size_t)B * C * (H * D);     // [3,H,64,64] bf16

    wprep<<<3 * H, 64, 0, stream>>>(Wq, Wk, Wv, Wt, kvraw);
    proj_kernel<<<BH * (N / 256), 256, 0, stream>>>(x, Wt, bq, bk, bv,
                                                    q, kvraw, Sg);
    kw_kernel<<<BH * (C / 64), 256, 0, stream>>>(kvraw, Sg, Wp, KWT);
    out_gemm<<<(BN / 128) * (C / 64), 256, 0, stream>>>(q, KWT, bp, out);
}